// Round 9
// baseline (496.349 us; speedup 1.0000x reference)
//
#include <hip/hip_runtime.h>

// Capsule routing: B=256, J=2, N=6912, E=16, D=8, 2 routing iters. All fp32.
// R19: R18 (quad-bcast) regressed -> reverted to R17 bodies exactly (141.3us).
// Remaining budget: fill ~41us (harness) + 2x kpass ~24-30 + 2x kred ~5 +
// ~25-40us of inter-dispatch gaps. This round removes 2 gaps: kred folded into
// the kpass dispatches as 64 appended reducer blocks (grid (CGX+16,4)).
// Producers: syncthreads -> threadfence(release, L2 writeback) -> agent-scope
// atomicAdd(ctr). Reducers: s_sleep-spin on acquire load until 2304, fence,
// then exact kred body. 64 spinners < 1024 resident slots -> no deadlock.
// Counters at end of ws, zeroed by an 8-byte hipMemsetAsync (capturable).
// Tripwires: absmax 2^-10 unchanged; VGPR/WRITE_SIZE identical to R17.
#define B_ 256
#define J_ 2
#define N_ 6912
#define E_ 16
#define D_ 8
#define NBT 12                 // n per block tile
#define CGX 576                // producer grid x; (CGX,4) = 2304 producers
#define RBX 16                 // reducer grid x extension: 16*4 = 64 reducers
#define TOT4 (J_*NBT*32)       // 768 f4 = 12.3 KB W tile
#define XROW 25                // f4 per b-row in x LDS (24 data + 1 pad)
#define XTOT4 (64*XROW)        // 1600 f4 = 25.6 KB x tile
#define NPROD (CGX*4)
#define OFS_CTR (8192 + (size_t)CGX*4*2048)   // float offset of counters in ws

// sum over the 8 eh-lanes (lane low-3 bits), pure VALU/DPP:
__device__ __forceinline__ float dpp_add8(float v){
  v += __int_as_float(__builtin_amdgcn_update_dpp(0, __float_as_int(v), 0xB1,  0xF, 0xF, true)); // quad_perm xor1
  v += __int_as_float(__builtin_amdgcn_update_dpp(0, __float_as_int(v), 0x4E,  0xF, 0xF, true)); // quad_perm xor2
  v += __int_as_float(__builtin_amdgcn_update_dpp(0, __float_as_int(v), 0x141, 0xF, 0xF, true)); // row_half_mirror xor7
  return v;
}

__device__ __forceinline__ float dot8(const float4 wa, const float4 wb,
                                      const float4 xa, const float4 xb, float a){
  a = fmaf(wa.x, xa.x, a); a = fmaf(wa.y, xa.y, a);
  a = fmaf(wa.z, xa.z, a); a = fmaf(wa.w, xa.w, a);
  a = fmaf(wb.x, xb.x, a); a = fmaf(wb.y, xb.y, a);
  a = fmaf(wb.z, xb.z, a); a = fmaf(wb.w, xb.w, a);
  return a;
}

// Stage W (swizzled) + x (padded rows) into LDS. All 9 global f4 loads issued
// before any LDS write (R16-proven no-spill pattern).
__device__ __forceinline__ void stageWX(const float* __restrict__ W,
                                        const float* __restrict__ x,
                                        int nb0, int by64, int tid,
                                        float4* __restrict__ Wl,
                                        float4* __restrict__ Xl){
  float4 bw[3], bx[6];
  #pragma unroll
  for (int r=0;r<3;++r){
    const int idx = r*256 + tid;                 // 0..767
    const int j  = (idx >= NBT*32) ? 1 : 0;
    const int r4 = idx - j*(NBT*32);
    bw[r] = *(const float4*)(W + ((size_t)j*N_ + nb0)*(E_*D_) + (size_t)r4*4);
  }
  #pragma unroll
  for (int r=0;r<6;++r){
    const int g = r*256 + tid;                   // 0..1535
    const int brow = g/24, c = g - brow*24;      // 24 f4 per b-row (12n x 8d)
    bx[r] = *(const float4*)(x + ((size_t)(by64 + brow)*N_ + nb0)*D_ + c*4);
  }
  #pragma unroll
  for (int r=0;r<3;++r){
    const int idx = r*256 + tid;
    const int u = idx & 31;
    Wl[(idx & ~31) | (u ^ (u>>3))] = bw[r];
  }
  #pragma unroll
  for (int r=0;r<6;++r){
    const int g = r*256 + tid;
    const int brow = g/24, c = g - brow*24;
    Xl[brow*XROW + c] = bx[r];
  }
}

// In-dispatch reduce (exact kred body): sum CGX chunks split-K by 2 + squash.
template<bool HALF>
__device__ __forceinline__ void reduce_tail(const float* __restrict__ partial,
                                            float* __restrict__ dst,
                                            float* __restrict__ sh,
                                            int r, int tid){
  const int o    = r*128 + (tid & 127);          // 64*128 = 8192 outputs
  const int half = tid >> 7;
  const int btile = o >> 11, q = o & 2047;
  const float* p = partial + (size_t)btile*2048 + q + (size_t)half*(CGX/2)*8192;
  float s = 0.f;
  #pragma unroll 24
  for (int cx=0; cx<CGX/2; ++cx) s += p[(size_t)cx*8192];
  if (half) sh[tid & 127] = s;
  __syncthreads();
  if (!half){
    s += sh[tid & 127];
    if (HALF) s *= 0.5f;
    float n2 = s*s;
    #pragma unroll
    for (int m=1; m<16; m<<=1) n2 += __shfl_xor(n2, m);
    dst[o] = s * (n2/(1.f+n2)) * rsqrtf(n2 + 1e-9f);
  }
}

__device__ __forceinline__ void wait_all(unsigned* ctr){
  while (__hip_atomic_load(ctr, __ATOMIC_ACQUIRE, __HIP_MEMORY_SCOPE_AGENT) < NPROD)
    __builtin_amdgcn_s_sleep(8);
  __threadfence();
}

__device__ __forceinline__ void signal_done(unsigned* ctr, int tid){
  __syncthreads();
  if (tid == 0){
    __threadfence();
    __hip_atomic_fetch_add(ctr, 1u, __ATOMIC_RELEASE, __HIP_MEMORY_SCOPE_AGENT);
  }
}

// ---------------- main path (2 fused dispatches) ----------------

__global__ __launch_bounds__(256, 4) void kpass1(const float* __restrict__ x,
                                                 const float* __restrict__ W,
                                                 float* __restrict__ partial,
                                                 float* __restrict__ v1,
                                                 unsigned* __restrict__ ctr)
{
  __shared__ float4 smem4[TOT4 + XTOT4];   // 37888 B
  const int tid = threadIdx.x;
  const int bx  = blockIdx.x, by = blockIdx.y;

  if (bx >= CGX){                          // reducer block
    wait_all(ctr);
    reduce_tail<true>(partial, v1, (float*)smem4, (bx-CGX)*4 + by, tid);
    return;
  }

  float4* Wl = smem4;
  float4* Xl = smem4 + TOT4;
  const int lane = tid & 63;
  const int wv   = __builtin_amdgcn_readfirstlane(tid >> 6);
  const int eh   = lane & 7;       // e-half slot: e in {eh, eh+8}
  const int bs   = lane >> 3;      // b slot: b_off = 8k + bs
  const int h    = wv >> 1;        // b half (32 b's each)
  const int p    = wv & 1;         // n parity
  const int nb0  = bx * NBT;

  const int sA0 = (eh*2)       ^ ((eh*2)>>3);
  const int sB0 = (eh*2+1)     ^ ((eh*2+1)>>3);
  const int sA1 = ((eh+8)*2)   ^ (((eh+8)*2)>>3);
  const int sB1 = ((eh+8)*2+1) ^ (((eh+8)*2+1)>>3);

  stageWX(W, x, nb0, by*64, tid, Wl, Xl);
  __syncthreads();

  const float4* Xr = Xl + (h*32 + bs)*XROW;   // k-th b adds 8*XROW
  float aJ0E0[4]={0,0,0,0}, aJ0E1[4]={0,0,0,0}, aJ1E0[4]={0,0,0,0}, aJ1E1[4]={0,0,0,0};
  #pragma unroll 1
  for (int ni=p; ni<NBT; ni+=2){
    const float4 w00a = Wl[ni*32 + sA0],       w00b = Wl[ni*32 + sB0];       // j0 e0
    const float4 w01a = Wl[ni*32 + sA1],       w01b = Wl[ni*32 + sB1];       // j0 e1
    const float4 w10a = Wl[(NBT+ni)*32 + sA0], w10b = Wl[(NBT+ni)*32 + sB0]; // j1 e0
    const float4 w11a = Wl[(NBT+ni)*32 + sA1], w11b = Wl[(NBT+ni)*32 + sB1]; // j1 e1
    #pragma unroll
    for (int k=0;k<4;++k){
      const float4 xa = Xr[k*(8*XROW) + ni*2];
      const float4 xb = Xr[k*(8*XROW) + ni*2 + 1];
      aJ0E0[k] = dot8(w00a,w00b, xa,xb, aJ0E0[k]);
      aJ0E1[k] = dot8(w01a,w01b, xa,xb, aJ0E1[k]);
      aJ1E0[k] = dot8(w10a,w10b, xa,xb, aJ1E0[k]);
      aJ1E1[k] = dot8(w11a,w11b, xa,xb, aJ1E1[k]);
    }
  }

  // n-parity merge: odd waves publish, even waves combine + store.
  __syncthreads();
  float* red = (float*)smem4;      // [h][32 b][33]: 2112 f32, overlays W tile
  if (p == 1){
    #pragma unroll
    for (int k=0;k<4;++k){
      const int base = h*1056 + (8*k+bs)*33 + eh;
      red[base]      = aJ0E0[k];
      red[base + 8]  = aJ0E1[k];
      red[base + 16] = aJ1E0[k];
      red[base + 24] = aJ1E1[k];
    }
  }
  __syncthreads();
  if (p == 0){
    float* dst = partial + (size_t)(bx*4 + by)*2048;
    #pragma unroll
    for (int k=0;k<4;++k){
      const int base = h*1056 + (8*k+bs)*33 + eh;
      const int go   = (h*32 + 8*k + bs)*32 + eh;
      dst[go]      = aJ0E0[k] + red[base];
      dst[go + 8]  = aJ0E1[k] + red[base + 8];
      dst[go + 16] = aJ1E0[k] + red[base + 16];
      dst[go + 24] = aJ1E1[k] + red[base + 24];
    }
  }
  signal_done(ctr, tid);
}

__global__ __launch_bounds__(256, 3) void kpass2(const float* __restrict__ x,
                                                 const float* __restrict__ W,
                                                 const float* __restrict__ v1,
                                                 float* __restrict__ partial,
                                                 float* __restrict__ out,
                                                 unsigned* __restrict__ ctr)
{
  __shared__ float4 smem4[TOT4 + XTOT4];
  const int tid = threadIdx.x;
  const int bx  = blockIdx.x, by = blockIdx.y;

  if (bx >= CGX){                          // reducer block
    wait_all(ctr);
    reduce_tail<false>(partial, out, (float*)smem4, (bx-CGX)*4 + by, tid);
    return;
  }

  float4* Wl = smem4;
  float4* Xl = smem4 + TOT4;
  const int lane = tid & 63;
  const int wv   = __builtin_amdgcn_readfirstlane(tid >> 6);
  const int eh   = lane & 7;
  const int bs   = lane >> 3;
  const int h    = wv >> 1;
  const int p    = wv & 1;
  const int nb0  = bx * NBT;
  const int b0g  = by*64;

  const int sA0 = (eh*2)       ^ ((eh*2)>>3);
  const int sB0 = (eh*2+1)     ^ ((eh*2+1)>>3);
  const int sA1 = ((eh+8)*2)   ^ (((eh+8)*2)>>3);
  const int sB1 = ((eh+8)*2+1) ^ (((eh+8)*2+1)>>3);

  stageWX(W, x, nb0, b0g, tid, Wl, Xl);
  // routing vector v1[b][j*16+e] for this thread's 4 b's x 2 j x 2 e
  float v00[4], v01[4], v10[4], v11[4];   // [jE]: j, e-half
  #pragma unroll
  for (int k=0;k<4;++k){
    const size_t vb = (size_t)(b0g + h*32 + 8*k + bs)*32 + eh;
    v00[k] = v1[vb];        // j0 e0
    v01[k] = v1[vb + 8];    // j0 e1
    v10[k] = v1[vb + 16];   // j1 e0
    v11[k] = v1[vb + 24];   // j1 e1
  }
  __syncthreads();

  const float4* Xr = Xl + (h*32 + bs)*XROW;
  float aJ0E0[4]={0,0,0,0}, aJ0E1[4]={0,0,0,0}, aJ1E0[4]={0,0,0,0}, aJ1E1[4]={0,0,0,0};
  #pragma unroll 1
  for (int ni=p; ni<NBT; ni+=2){
    const float4 w00a = Wl[ni*32 + sA0],       w00b = Wl[ni*32 + sB0];
    const float4 w01a = Wl[ni*32 + sA1],       w01b = Wl[ni*32 + sB1];
    const float4 w10a = Wl[(NBT+ni)*32 + sA0], w10b = Wl[(NBT+ni)*32 + sB0];
    const float4 w11a = Wl[(NBT+ni)*32 + sA1], w11b = Wl[(NBT+ni)*32 + sB1];
    #pragma unroll
    for (int k=0;k<4;++k){
      const float4 xa = Xr[k*(8*XROW) + ni*2];
      const float4 xb = Xr[k*(8*XROW) + ni*2 + 1];
      const float u00 = dot8(w00a,w00b, xa,xb, 0.f);
      const float u01 = dot8(w01a,w01b, xa,xb, 0.f);
      const float u10 = dot8(w10a,w10b, xa,xb, 0.f);
      const float u11 = dot8(w11a,w11b, xa,xb, 0.f);
      // delta = l1 - l0 over all 16 e: in-thread 2e + 8-lane DPP
      float t = v10[k]*u10;
      t = fmaf(v11[k], u11, t);
      t = fmaf(-v00[k], u00, t);
      t = fmaf(-v01[k], u01, t);
      t = dpp_add8(t);
      const float c0 = __builtin_amdgcn_rcpf(1.f + __expf(t));   // softmax over 2 caps
      const float c1 = 1.f - c0;
      aJ0E0[k] = fmaf(c0, u00, aJ0E0[k]);
      aJ0E1[k] = fmaf(c0, u01, aJ0E1[k]);
      aJ1E0[k] = fmaf(c1, u10, aJ1E0[k]);
      aJ1E1[k] = fmaf(c1, u11, aJ1E1[k]);
    }
  }

  __syncthreads();
  float* red = (float*)smem4;
  if (p == 1){
    #pragma unroll
    for (int k=0;k<4;++k){
      const int base = h*1056 + (8*k+bs)*33 + eh;
      red[base]      = aJ0E0[k];
      red[base + 8]  = aJ0E1[k];
      red[base + 16] = aJ1E0[k];
      red[base + 24] = aJ1E1[k];
    }
  }
  __syncthreads();
  if (p == 0){
    float* dst = partial + (size_t)(bx*4 + by)*2048;
    #pragma unroll
    for (int k=0;k<4;++k){
      const int base = h*1056 + (8*k+bs)*33 + eh;
      const int go   = (h*32 + 8*k + bs)*32 + eh;
      dst[go]      = aJ0E0[k] + red[base];
      dst[go + 8]  = aJ0E1[k] + red[base + 8];
      dst[go + 16] = aJ1E0[k] + red[base + 16];
      dst[go + 24] = aJ1E1[k] + red[base + 24];
    }
  }
  signal_done(ctr, tid);
}

// ---------------- fallback: monolithic (no ws) ----------------
#define NT 512
__global__ __launch_bounds__(NT) void kmono(const float* __restrict__ x,
                                            const float* __restrict__ W,
                                            float* __restrict__ out)
{
  const int b    = blockIdx.x;
  const int tid  = threadIdx.x;
  const int wv   = tid >> 6;
  const int lane = tid & 63;
  __shared__ float wred[8*33];
  __shared__ float vsh[32];

  float acc[32];
  #pragma unroll
  for (int i=0;i<32;++i) acc[i]=0.f;
  for (int n = tid; n < N_; n += NT){
    const float4 xa = *(const float4*)(x + ((size_t)b*N_ + n)*D_);
    const float4 xb = *(const float4*)(x + ((size_t)b*N_ + n)*D_ + 4);
    #pragma unroll
    for (int j=0;j<J_;++j){
      const float* wp = W + ((size_t)j*N_ + n)*(E_*D_);
      #pragma unroll
      for (int e=0;e<E_;++e){
        const float4 wa = *(const float4*)(wp + e*8);
        const float4 wb = *(const float4*)(wp + e*8 + 4);
        float a = acc[j*16+e];
        a = fmaf(wa.x,xa.x,a); a = fmaf(wa.y,xa.y,a); a = fmaf(wa.z,xa.z,a); a = fmaf(wa.w,xa.w,a);
        a = fmaf(wb.x,xb.x,a); a = fmaf(wb.y,xb.y,a); a = fmaf(wb.z,xb.z,a); a = fmaf(wb.w,xb.w,a);
        acc[j*16+e] = a;
      }
    }
  }
  #pragma unroll
  for (int i=0;i<32;++i){
    float v = acc[i];
    #pragma unroll
    for (int off=32; off; off>>=1) v += __shfl_xor(v, off);
    acc[i] = v;
  }
  if (lane == 0){
    #pragma unroll
    for (int i=0;i<32;++i) wred[wv*33 + i] = acc[i];
  }
  __syncthreads();
  if (tid < 32){
    float s = 0.f;
    #pragma unroll
    for (int w=0;w<8;++w) s += wred[w*33 + tid];
    wred[tid] = 0.5f * s;
  }
  __syncthreads();
  if (tid < 32){
    const int j = tid >> 4; float n2 = 0.f;
    #pragma unroll
    for (int e=0;e<16;++e){ const float sv = wred[j*16+e]; n2 = fmaf(sv,sv,n2); }
    vsh[tid] = wred[tid] * (n2/(1.f+n2)) * rsqrtf(n2 + 1e-9f);
  }
  __syncthreads();
  float vv[32];
  #pragma unroll
  for (int i=0;i<32;++i) vv[i] = vsh[i];

  #pragma unroll
  for (int i=0;i<32;++i) acc[i]=0.f;
  for (int n = tid; n < N_; n += NT){
    const float4 xa = *(const float4*)(x + ((size_t)b*N_ + n)*D_);
    const float4 xb = *(const float4*)(x + ((size_t)b*N_ + n)*D_ + 4);
    float u[32];
    #pragma unroll
    for (int j=0;j<J_;++j){
      const float* wp = W + ((size_t)j*N_ + n)*(E_*D_);
      #pragma unroll
      for (int e=0;e<E_;++e){
        const float4 wa = *(const float4*)(wp + e*8);
        const float4 wb = *(const float4*)(wp + e*8 + 4);
        float a;
        a = wa.x*xa.x; a = fmaf(wa.y,xa.y,a); a = fmaf(wa.z,xa.z,a); a = fmaf(wa.w,xa.w,a);
        a = fmaf(wb.x,xb.x,a); a = fmaf(wb.y,xb.y,a); a = fmaf(wb.z,xb.z,a); a = fmaf(wb.w,xb.w,a);
        u[j*16+e] = a;
      }
    }
    float l0=0.f, l1=0.f;
    #pragma unroll
    for (int e=0;e<16;++e){ l0 = fmaf(vv[e],u[e],l0); l1 = fmaf(vv[16+e],u[16+e],l1); }
    const float c0 = 1.f/(1.f + __expf(l1 - l0));
    const float c1 = 1.f - c0;
    #pragma unroll
    for (int e=0;e<16;++e){ acc[e] = fmaf(c0,u[e],acc[e]); acc[16+e] = fmaf(c1,u[16+e],acc[16+e]); }
  }
  #pragma unroll
  for (int i=0;i<32;++i){
    float v = acc[i];
    #pragma unroll
    for (int off=32; off; off>>=1) v += __shfl_xor(v, off);
    acc[i] = v;
  }
  __syncthreads();
  if (lane == 0){
    #pragma unroll
    for (int i=0;i<32;++i) wred[wv*33 + i] = acc[i];
  }
  __syncthreads();
  if (tid < 32){
    float s = 0.f;
    #pragma unroll
    for (int w=0;w<8;++w) s += wred[w*33 + tid];
    wred[tid] = s;
  }
  __syncthreads();
  if (tid < 32){
    const int j = tid >> 4; float n2 = 0.f;
    #pragma unroll
    for (int e=0;e<16;++e){ const float sv = wred[j*16+e]; n2 = fmaf(sv,sv,n2); }
    out[(size_t)b*32 + tid] = wred[tid] * (n2/(1.f+n2)) * rsqrtf(n2 + 1e-9f);
  }
}

extern "C" void kernel_launch(void* const* d_in, const int* in_sizes, int n_in,
                              void* d_out, int out_size, void* d_ws, size_t ws_size,
                              hipStream_t stream)
{
  const float* x = (const float*)d_in[0];   // [256,6912,8]
  const float* W = (const float*)d_in[1];   // [2,6912,16,8]
  if (n_in >= 2 && in_sizes[0] < in_sizes[1]){
    x = (const float*)d_in[1]; W = (const float*)d_in[0];
  }
  float* out = (float*)d_out;               // fp32 [256,2,16]

  const size_t need = (OFS_CTR + 2) * sizeof(float);   // ~18.9 MB + counters

  if (ws_size >= need){
    float* wsf      = (float*)d_ws;
    float* v1       = wsf;                  // 8192 floats
    float* partial  = wsf + 8192;           // CGX*4*2048 floats
    unsigned* ctrs  = (unsigned*)(wsf + OFS_CTR);

    hipMemsetAsync(ctrs, 0, 2*sizeof(unsigned), stream);
    kpass1<<<dim3(CGX+RBX,4), 256, 0, stream>>>(x, W, partial, v1, ctrs);
    kpass2<<<dim3(CGX+RBX,4), 256, 0, stream>>>(x, W, v1, partial, out, ctrs+1);
  } else {
    kmono<<<B_, NT, 0, stream>>>(x, W, out);
  }
}

// Round 10
// 147.846 us; speedup vs baseline: 3.3572x; 3.3572x over previous
//
#include <hip/hip_runtime.h>

// Capsule routing: B=256, J=2, N=6912, E=16, D=8, 2 routing iters. All fp32.
// R20: R19 post-mortem: in-dispatch cross-XCD sync (threadfence release + agent
// acquire polling) poisons L2 coherence -> 230us/pass @ VALU 5%. Third failure
// of intra-dispatch global sync (R13 coop, R19 spin) => 4 launches is the floor.
// This round: revert launcher/sync to R17 (141.3us best) and cut LDS-instr in
// the bodies: e4xb4 lane map (eh=lane&3, bs=lane>>2; thread owns e=eh+4m x 2j,
// b=bs+16k; waves split n 4-way). W frags (16 b128) held across k-loop; x read
// DIRECTLY per k (8 b128/n) - no R18 DPP gather. 24 b128 / 256 FMA (rho=0.094,
// -25% vs R17). Stage/vj/merge/epilogue math byte-identical to verified R18.
// Launch bounds (256,4)/(256,3) as R17. VGPR est p1~115 p2~155.
// Tripwires: WRITE_SIZE ~20MB/pass (spill!), dur >= 141 kills the LDS model.
#define B_ 256
#define J_ 2
#define N_ 6912
#define E_ 16
#define D_ 8
#define NBT 12                 // n per block tile (= 4 waves x 3 n)
#define CGX 576                // grid (CGX,4) = 2304 blocks
#define TOT4 (J_*NBT*32)       // 768 f4 = 12.3 KB W tile
#define XROW 25                // f4 per b-row in x LDS (24 data + 1 pad)
#define XTOT4 (64*XROW)        // 1600 f4 = 25.6 KB x tile

// all-reduce sum over the 4 quad lanes (eh 0-3, fixed bs):
__device__ __forceinline__ float dpp_add4(float v){
  v += __int_as_float(__builtin_amdgcn_update_dpp(0, __float_as_int(v), 0xB1, 0xF, 0xF, true)); // xor1
  v += __int_as_float(__builtin_amdgcn_update_dpp(0, __float_as_int(v), 0x4E, 0xF, 0xF, true)); // xor2
  return v;
}

__device__ __forceinline__ float dot8(const float4 wa, const float4 wb,
                                      const float4 xa, const float4 xb, float a){
  a = fmaf(wa.x, xa.x, a); a = fmaf(wa.y, xa.y, a);
  a = fmaf(wa.z, xa.z, a); a = fmaf(wa.w, xa.w, a);
  a = fmaf(wb.x, xb.x, a); a = fmaf(wb.y, xb.y, a);
  a = fmaf(wb.z, xb.z, a); a = fmaf(wb.w, xb.w, a);
  return a;
}

// Stage W (16B-unit XOR swizzle per 32-unit row) + x (rows padded to XROW f4)
// into LDS. All 9 global f4 loads issued before any LDS write (R16-proven).
__device__ __forceinline__ void stageWX(const float* __restrict__ W,
                                        const float* __restrict__ x,
                                        int nb0, int by64, int tid,
                                        float4* __restrict__ Wl,
                                        float4* __restrict__ Xl){
  float4 bw[3], bx[6];
  #pragma unroll
  for (int r=0;r<3;++r){
    const int idx = r*256 + tid;                 // 0..767
    const int j  = (idx >= NBT*32) ? 1 : 0;
    const int r4 = idx - j*(NBT*32);
    bw[r] = *(const float4*)(W + ((size_t)j*N_ + nb0)*(E_*D_) + (size_t)r4*4);
  }
  #pragma unroll
  for (int r=0;r<6;++r){
    const int g = r*256 + tid;                   // 0..1535
    const int brow = g/24, c = g - brow*24;      // 24 f4 per b-row (12n x 8d)
    bx[r] = *(const float4*)(x + ((size_t)(by64 + brow)*N_ + nb0)*D_ + c*4);
  }
  #pragma unroll
  for (int r=0;r<3;++r){
    const int idx = r*256 + tid;
    const int u = idx & 31;
    Wl[(idx & ~31) | (u ^ (u>>3))] = bw[r];
  }
  #pragma unroll
  for (int r=0;r<6;++r){
    const int g = r*256 + tid;
    const int brow = g/24, c = g - brow*24;
    Xl[brow*XROW + c] = bx[r];
  }
}

// ---------------- main path (4 launches) ----------------

__global__ __launch_bounds__(256, 4) void kpass1(const float* __restrict__ x,
                                                 const float* __restrict__ W,
                                                 float* __restrict__ partial)
{
  __shared__ float4 smem4[TOT4 + XTOT4];   // 37888 B (merge overlays 1536 f4)
  float4* Wl = smem4;
  float4* Xl = smem4 + TOT4;
  const int tid  = threadIdx.x;
  const int lane = tid & 63;
  const int wv   = __builtin_amdgcn_readfirstlane(tid >> 6);
  const int eh   = lane & 3;       // e-slot: e = eh + 4m
  const int bs   = lane >> 2;      // b-slot: b = bs + 16k
  const int nb0  = blockIdx.x * NBT;

  int sA[4], sB[4];
  #pragma unroll
  for (int m=0;m<4;++m){
    const int uA = 2*(eh+4*m), uB = uA+1;
    sA[m] = uA ^ (uA>>3);
    sB[m] = uB ^ (uB>>3);
  }

  stageWX(W, x, nb0, blockIdx.y*64, tid, Wl, Xl);
  __syncthreads();

  const float4* Xr = Xl + bs*XROW;             // k-th b adds 16*XROW
  float acc[32];                               // [(j*4+m)*4 + k]
  #pragma unroll
  for (int i=0;i<32;++i) acc[i]=0.f;

  #pragma unroll 1
  for (int t=0; t<3; ++t){
    const int ni = wv + 4*t;                   // wave-owned n slice
    float4 wA[8], wB[8];                       // q = j*4+m
    #pragma unroll
    for (int j=0;j<2;++j)
      #pragma unroll
      for (int m=0;m<4;++m){
        wA[j*4+m] = Wl[(j*NBT+ni)*32 + sA[m]];
        wB[j*4+m] = Wl[(j*NBT+ni)*32 + sB[m]];
      }
    #pragma unroll
    for (int k=0;k<4;++k){
      const float4 xa = Xr[(k*16)*XROW + ni*2];
      const float4 xb = Xr[(k*16)*XROW + ni*2 + 1];
      #pragma unroll
      for (int q=0;q<8;++q)
        acc[q*4+k] = dot8(wA[q], wB[q], xa, xb, acc[q*4+k]);
    }
  }

  // 4-way n-merge: waves 1-3 publish 8 f4 each; wave 0 sums + stores.
  __syncthreads();
  float4* mb = smem4;                          // [q][w][lane] f4, 1536 f4
  if (wv){
    #pragma unroll
    for (int q=0;q<8;++q)
      mb[(q*3 + (wv-1))*64 + lane] = make_float4(acc[q*4],acc[q*4+1],acc[q*4+2],acc[q*4+3]);
  }
  __syncthreads();
  if (wv == 0){
    float* dst = partial + (size_t)(blockIdx.x*4 + blockIdx.y)*2048;
    #pragma unroll
    for (int q=0;q<8;++q){
      float4 s = make_float4(acc[q*4],acc[q*4+1],acc[q*4+2],acc[q*4+3]);
      #pragma unroll
      for (int w=0;w<3;++w){
        const float4 o = mb[(q*3+w)*64 + lane];
        s.x+=o.x; s.y+=o.y; s.z+=o.z; s.w+=o.w;
      }
      const int be = (q>>2)*16 + eh + 4*(q&3);  // j*16 + e
      dst[(bs     )*32 + be] = s.x;
      dst[(bs + 16)*32 + be] = s.y;
      dst[(bs + 32)*32 + be] = s.z;
      dst[(bs + 48)*32 + be] = s.w;
    }
  }
}

__global__ __launch_bounds__(256, 3) void kpass2(const float* __restrict__ x,
                                                 const float* __restrict__ W,
                                                 const float* __restrict__ v1,
                                                 float* __restrict__ partial)
{
  __shared__ float4 smem4[TOT4 + XTOT4];
  float4* Wl = smem4;
  float4* Xl = smem4 + TOT4;
  const int tid  = threadIdx.x;
  const int lane = tid & 63;
  const int wv   = __builtin_amdgcn_readfirstlane(tid >> 6);
  const int eh   = lane & 3;
  const int bs   = lane >> 2;
  const int nb0  = blockIdx.x * NBT;
  const int b0g  = blockIdx.y*64;

  int sA[4], sB[4];
  #pragma unroll
  for (int m=0;m<4;++m){
    const int uA = 2*(eh+4*m), uB = uA+1;
    sA[m] = uA ^ (uA>>3);
    sB[m] = uB ^ (uB>>3);
  }

  stageWX(W, x, nb0, b0g, tid, Wl, Xl);
  float vj[32];                                // [(j*4+m)*4 + k]
  #pragma unroll
  for (int j=0;j<2;++j)
    #pragma unroll
    for (int m=0;m<4;++m)
      #pragma unroll
      for (int k=0;k<4;++k)
        vj[(j*4+m)*4+k] = v1[(size_t)(b0g + bs + 16*k)*32 + j*16 + eh + 4*m];
  __syncthreads();

  const float4* Xr = Xl + bs*XROW;
  float acc[32];
  #pragma unroll
  for (int i=0;i<32;++i) acc[i]=0.f;

  #pragma unroll 1
  for (int t=0; t<3; ++t){
    const int ni = wv + 4*t;
    float4 wA[8], wB[8];
    #pragma unroll
    for (int j=0;j<2;++j)
      #pragma unroll
      for (int m=0;m<4;++m){
        wA[j*4+m] = Wl[(j*NBT+ni)*32 + sA[m]];
        wB[j*4+m] = Wl[(j*NBT+ni)*32 + sB[m]];
      }
    #pragma unroll
    for (int k=0;k<4;++k){
      const float4 xa = Xr[(k*16)*XROW + ni*2];
      const float4 xb = Xr[(k*16)*XROW + ni*2 + 1];
      float u[8];
      #pragma unroll
      for (int q=0;q<8;++q)
        u[q] = dot8(wA[q], wB[q], xa, xb, 0.f);
      float tt = 0.f;                          // l1 - l0, partial over thread e's
      #pragma unroll
      for (int m=0;m<4;++m){
        tt = fmaf(vj[(4+m)*4+k], u[4+m], tt);
        tt = fmaf(-vj[m*4+k],    u[m],   tt);
      }
      tt = dpp_add4(tt);                       // full 16-e sum (quad = fixed b)
      const float c0 = __builtin_amdgcn_rcpf(1.f + __expf(tt));  // softmax (2 caps)
      const float c1 = 1.f - c0;
      #pragma unroll
      for (int m=0;m<4;++m){
        acc[m*4+k]     = fmaf(c0, u[m],   acc[m*4+k]);
        acc[(4+m)*4+k] = fmaf(c1, u[4+m], acc[(4+m)*4+k]);
      }
    }
  }

  __syncthreads();
  float4* mb = smem4;
  if (wv){
    #pragma unroll
    for (int q=0;q<8;++q)
      mb[(q*3 + (wv-1))*64 + lane] = make_float4(acc[q*4],acc[q*4+1],acc[q*4+2],acc[q*4+3]);
  }
  __syncthreads();
  if (wv == 0){
    float* dst = partial + (size_t)(blockIdx.x*4 + blockIdx.y)*2048;
    #pragma unroll
    for (int q=0;q<8;++q){
      float4 s = make_float4(acc[q*4],acc[q*4+1],acc[q*4+2],acc[q*4+3]);
      #pragma unroll
      for (int w=0;w<3;++w){
        const float4 o = mb[(q*3+w)*64 + lane];
        s.x+=o.x; s.y+=o.y; s.z+=o.z; s.w+=o.w;
      }
      const int be = (q>>2)*16 + eh + 4*(q&3);
      dst[(bs     )*32 + be] = s.x;
      dst[(bs + 16)*32 + be] = s.y;
      dst[(bs + 32)*32 + be] = s.z;
      dst[(bs + 48)*32 + be] = s.w;
    }
  }
}

// Fused reduce (sum CGX chunk-partials, split-K by 2) + squash.
// grid 64 x 256: tid&127 -> output within block's 128, tid>>7 -> K-half.
template<bool HALF>
__global__ __launch_bounds__(256) void kred(const float* __restrict__ partial,
                                            float* __restrict__ dst)
{
  __shared__ float sh[128];
  const int tid  = threadIdx.x;
  const int o    = blockIdx.x*128 + (tid & 127);   // 64*128 = 8192 outputs
  const int half = tid >> 7;
  const int btile = o >> 11, q = o & 2047;
  const float* p = partial + (size_t)btile*2048 + q + (size_t)half*(CGX/2)*8192;
  float s = 0.f;
  #pragma unroll 24
  for (int cx=0; cx<CGX/2; ++cx) s += p[(size_t)cx*8192];
  if (half) sh[tid & 127] = s;
  __syncthreads();
  if (!half){
    s += sh[tid & 127];
    if (HALF) s *= 0.5f;
    float n2 = s*s;
    #pragma unroll
    for (int m=1; m<16; m<<=1) n2 += __shfl_xor(n2, m);
    dst[o] = s * (n2/(1.f+n2)) * rsqrtf(n2 + 1e-9f);
  }
}

// ---------------- fallback: monolithic (no ws) ----------------
#define NT 512
__global__ __launch_bounds__(NT) void kmono(const float* __restrict__ x,
                                            const float* __restrict__ W,
                                            float* __restrict__ out)
{
  const int b    = blockIdx.x;
  const int tid  = threadIdx.x;
  const int wv   = tid >> 6;
  const int lane = tid & 63;
  __shared__ float wred[8*33];
  __shared__ float vsh[32];

  float acc[32];
  #pragma unroll
  for (int i=0;i<32;++i) acc[i]=0.f;
  for (int n = tid; n < N_; n += NT){
    const float4 xa = *(const float4*)(x + ((size_t)b*N_ + n)*D_);
    const float4 xb = *(const float4*)(x + ((size_t)b*N_ + n)*D_ + 4);
    #pragma unroll
    for (int j=0;j<J_;++j){
      const float* wp = W + ((size_t)j*N_ + n)*(E_*D_);
      #pragma unroll
      for (int e=0;e<E_;++e){
        const float4 wa = *(const float4*)(wp + e*8);
        const float4 wb = *(const float4*)(wp + e*8 + 4);
        float a = acc[j*16+e];
        a = fmaf(wa.x,xa.x,a); a = fmaf(wa.y,xa.y,a); a = fmaf(wa.z,xa.z,a); a = fmaf(wa.w,xa.w,a);
        a = fmaf(wb.x,xb.x,a); a = fmaf(wb.y,xb.y,a); a = fmaf(wb.z,xb.z,a); a = fmaf(wb.w,xb.w,a);
        acc[j*16+e] = a;
      }
    }
  }
  #pragma unroll
  for (int i=0;i<32;++i){
    float v = acc[i];
    #pragma unroll
    for (int off=32; off; off>>=1) v += __shfl_xor(v, off);
    acc[i] = v;
  }
  if (lane == 0){
    #pragma unroll
    for (int i=0;i<32;++i) wred[wv*33 + i] = acc[i];
  }
  __syncthreads();
  if (tid < 32){
    float s = 0.f;
    #pragma unroll
    for (int w=0;w<8;++w) s += wred[w*33 + tid];
    wred[tid] = 0.5f * s;
  }
  __syncthreads();
  if (tid < 32){
    const int j = tid >> 4; float n2 = 0.f;
    #pragma unroll
    for (int e=0;e<16;++e){ const float sv = wred[j*16+e]; n2 = fmaf(sv,sv,n2); }
    vsh[tid] = wred[tid] * (n2/(1.f+n2)) * rsqrtf(n2 + 1e-9f);
  }
  __syncthreads();
  float vv[32];
  #pragma unroll
  for (int i=0;i<32;++i) vv[i] = vsh[i];

  #pragma unroll
  for (int i=0;i<32;++i) acc[i]=0.f;
  for (int n = tid; n < N_; n += NT){
    const float4 xa = *(const float4*)(x + ((size_t)b*N_ + n)*D_);
    const float4 xb = *(const float4*)(x + ((size_t)b*N_ + n)*D_ + 4);
    float u[32];
    #pragma unroll
    for (int j=0;j<J_;++j){
      const float* wp = W + ((size_t)j*N_ + n)*(E_*D_);
      #pragma unroll
      for (int e=0;e<E_;++e){
        const float4 wa = *(const float4*)(wp + e*8);
        const float4 wb = *(const float4*)(wp + e*8 + 4);
        float a;
        a = wa.x*xa.x; a = fmaf(wa.y,xa.y,a); a = fmaf(wa.z,xa.z,a); a = fmaf(wa.w,xa.w,a);
        a = fmaf(wb.x,xb.x,a); a = fmaf(wb.y,xb.y,a); a = fmaf(wb.z,xb.z,a); a = fmaf(wb.w,xb.w,a);
        u[j*16+e] = a;
      }
    }
    float l0=0.f, l1=0.f;
    #pragma unroll
    for (int e=0;e<16;++e){ l0 = fmaf(vv[e],u[e],l0); l1 = fmaf(vv[16+e],u[16+e],l1); }
    const float c0 = 1.f/(1.f + __expf(l1 - l0));
    const float c1 = 1.f - c0;
    #pragma unroll
    for (int e=0;e<16;++e){ acc[e] = fmaf(c0,u[e],acc[e]); acc[16+e] = fmaf(c1,u[16+e],acc[16+e]); }
  }
  #pragma unroll
  for (int i=0;i<32;++i){
    float v = acc[i];
    #pragma unroll
    for (int off=32; off; off>>=1) v += __shfl_xor(v, off);
    acc[i] = v;
  }
  __syncthreads();
  if (lane == 0){
    #pragma unroll
    for (int i=0;i<32;++i) wred[wv*33 + i] = acc[i];
  }
  __syncthreads();
  if (tid < 32){
    float s = 0.f;
    #pragma unroll
    for (int w=0;w<8;++w) s += wred[w*33 + tid];
    wred[tid] = s;
  }
  __syncthreads();
  if (tid < 32){
    const int j = tid >> 4; float n2 = 0.f;
    #pragma unroll
    for (int e=0;e<16;++e){ const float sv = wred[j*16+e]; n2 = fmaf(sv,sv,n2); }
    out[(size_t)b*32 + tid] = wred[tid] * (n2/(1.f+n2)) * rsqrtf(n2 + 1e-9f);
  }
}

extern "C" void kernel_launch(void* const* d_in, const int* in_sizes, int n_in,
                              void* d_out, int out_size, void* d_ws, size_t ws_size,
                              hipStream_t stream)
{
  const float* x = (const float*)d_in[0];   // [256,6912,8]
  const float* W = (const float*)d_in[1];   // [2,6912,16,8]
  if (n_in >= 2 && in_sizes[0] < in_sizes[1]){
    x = (const float*)d_in[1]; W = (const float*)d_in[0];
  }
  float* out = (float*)d_out;               // fp32 [256,2,16]

  const size_t need = (size_t)(8192 + (size_t)CGX*4*2048) * sizeof(float);  // ~18.9 MB

  if (ws_size >= need){
    float* wsf     = (float*)d_ws;
    float* v1      = wsf;           // 8192 floats
    float* partial = wsf + 8192;    // CGX*4*2048 floats
    kpass1<<<dim3(CGX,4), 256, 0, stream>>>(x, W, partial);
    kred<true ><<<64, 256, 0, stream>>>(partial, v1);
    kpass2<<<dim3(CGX,4), 256, 0, stream>>>(x, W, v1, partial);
    kred<false><<<64, 256, 0, stream>>>(partial, out);
  } else {
    kmono<<<B_, NT, 0, stream>>>(x, W, out);
  }
}